// Round 1
// baseline (1284.255 us; speedup 1.0000x reference)
//
#include <hip/hip_runtime.h>

typedef __attribute__((ext_vector_type(8))) __bf16 bf16x8;
typedef __attribute__((ext_vector_type(4))) float f32x4;

#define MFMA16(a, b, c) __builtin_amdgcn_mfma_f32_16x16x32_bf16((a), (b), (c), 0, 0, 0)

__device__ __forceinline__ unsigned short f2bf(float f) {
    unsigned int u = __builtin_bit_cast(unsigned int, f);
    u += 0x7fffu + ((u >> 16) & 1u);
    return (unsigned short)(u >> 16);
}

__device__ __forceinline__ float wave_sum(float v) {
#pragma unroll
    for (int off = 32; off; off >>= 1) v += __shfl_xor(v, off, 64);
    return v;
}
__device__ __forceinline__ float wave_max(float v) {
#pragma unroll
    for (int off = 32; off; off >>= 1) v = fmaxf(v, __shfl_xor(v, off, 64));
    return v;
}

// ---------------- fp32 -> bf16 cast (weights) ----------------
__global__ __launch_bounds__(256) void k_cvt(const float* __restrict__ s,
                                             unsigned short* __restrict__ d, int n) {
    int i = (blockIdx.x * 256 + threadIdx.x) * 4;
    if (i >= n) return;
    float4 v = *reinterpret_cast<const float4*>(s + i);
    ushort4 o;
    o.x = f2bf(v.x); o.y = f2bf(v.y); o.z = f2bf(v.z); o.w = f2bf(v.w);
    *reinterpret_cast<ushort4*>(d + i) = o;
}

// ---------------- LN1 over C=256, one wave per pixel -> bf16 ----------------
__global__ __launch_bounds__(256) void k_ln_bf(const float* __restrict__ x,
                                               const float* __restrict__ g,
                                               const float* __restrict__ b,
                                               unsigned short* __restrict__ o) {
    int wave = threadIdx.x >> 6, lane = threadIdx.x & 63;
    long long pix = (long long)blockIdx.x * 4 + wave;
    const float* row = x + pix * 256;
    float4 v = *reinterpret_cast<const float4*>(row + lane * 4);
    float s = v.x + v.y + v.z + v.w;
    float s2 = v.x * v.x + v.y * v.y + v.z * v.z + v.w * v.w;
    s = wave_sum(s); s2 = wave_sum(s2);
    float mean = s * (1.f / 256.f);
    float rstd = rsqrtf(s2 * (1.f / 256.f) - mean * mean + 1e-5f);
    float4 gg = *reinterpret_cast<const float4*>(g + lane * 4);
    float4 bb = *reinterpret_cast<const float4*>(b + lane * 4);
    ushort4 ov;
    ov.x = f2bf((v.x - mean) * rstd * gg.x + bb.x);
    ov.y = f2bf((v.y - mean) * rstd * gg.y + bb.y);
    ov.z = f2bf((v.z - mean) * rstd * gg.z + bb.z);
    ov.w = f2bf((v.w - mean) * rstd * gg.w + bb.w);
    *reinterpret_cast<ushort4*>(o + pix * 256 + lane * 4) = ov;
}

// ---------------- down-proj: [2048,16384]x[256,16384]^T, A addressed through unfold ----------------
__global__ __launch_bounds__(256) void k_gemm_down(const unsigned short* __restrict__ xln,
                                                   const unsigned short* __restrict__ wd,
                                                   const float* __restrict__ bd,
                                                   unsigned short* __restrict__ y) {
    int wave = threadIdx.x >> 6, lane = threadIdx.x & 63, quad = lane >> 4, l16 = lane & 15;
    int m0 = blockIdx.x * 64 + wave * 16;
    int n0 = blockIdx.y * 64;
    int m = m0 + l16;
    int bb = m >> 10, r0 = (m >> 5) & 31, r1 = m & 31;
    const unsigned short* abase = xln + ((long long)bb << 24) + ((long long)(r0 * 8) << 16) + (r1 * 8) * 256;
    f32x4 acc[4] = {};
    for (int kb = 0; kb < 16384; kb += 32) {
        int off = kb + quad * 8;
        int aoff = ((off >> 11) << 16) | (((off >> 8) & 7) << 8) | (off & 255);
        bf16x8 a = *reinterpret_cast<const bf16x8*>(abase + aoff);
#pragma unroll
        for (int ni = 0; ni < 4; ni++) {
            bf16x8 bv = *reinterpret_cast<const bf16x8*>(wd + (long long)(n0 + ni * 16 + l16) * 16384 + off);
            acc[ni] = MFMA16(a, bv, acc[ni]);
        }
    }
    int rbase = m0 + quad * 4;
#pragma unroll
    for (int ni = 0; ni < 4; ni++) {
        int n = n0 + ni * 16 + l16;
        float bias = bd[n];
#pragma unroll
        for (int r = 0; r < 4; r++)
            y[(long long)(rbase + r) * 256 + n] = f2bf(acc[ni][r] + bias);
    }
}

// ---------------- qkv: [2048,256]x[768,256]^T, scatter to q, k, v^T (bf16) ----------------
__global__ __launch_bounds__(256) void k_gemm_qkv(const unsigned short* __restrict__ yd,
                                                  const unsigned short* __restrict__ wq,
                                                  const float* __restrict__ bq,
                                                  unsigned short* __restrict__ q,
                                                  unsigned short* __restrict__ k,
                                                  unsigned short* __restrict__ vT) {
    int wave = threadIdx.x >> 6, lane = threadIdx.x & 63, quad = lane >> 4, l16 = lane & 15;
    int m0 = blockIdx.x * 64 + wave * 16;
    int n0 = blockIdx.y * 64;
    const unsigned short* arow = yd + (long long)(m0 + l16) * 256;
    f32x4 acc[4] = {};
    for (int kb = 0; kb < 256; kb += 32) {
        bf16x8 a = *reinterpret_cast<const bf16x8*>(arow + kb + quad * 8);
#pragma unroll
        for (int ni = 0; ni < 4; ni++) {
            bf16x8 bv = *reinterpret_cast<const bf16x8*>(wq + (long long)(n0 + ni * 16 + l16) * 256 + kb + quad * 8);
            acc[ni] = MFMA16(a, bv, acc[ni]);
        }
    }
#pragma unroll
    for (int ni = 0; ni < 4; ni++) {
        int n = n0 + ni * 16 + l16;
        float bias = bq[n];
        int t = n >> 8, h = (n >> 5) & 7, d = n & 31;
#pragma unroll
        for (int r = 0; r < 4; r++) {
            int m = m0 + quad * 4 + r;
            int bh = ((m >> 10) << 3) | h;
            int l = m & 1023;
            unsigned short val = f2bf(acc[ni][r] + bias);
            if (t == 0)      q[((long long)bh * 1024 + l) * 32 + d] = val;
            else if (t == 1) k[((long long)bh * 1024 + l) * 32 + d] = val;
            else             vT[((long long)bh * 32 + d) * 1024 + l] = val;
        }
    }
}

// ---------------- scores: S = scale*q@k^T + rpe (fp32) ----------------
__global__ __launch_bounds__(256) void k_score(const unsigned short* __restrict__ q,
                                               const unsigned short* __restrict__ k,
                                               const float* __restrict__ rpe,
                                               float* __restrict__ S) {
    int wave = threadIdx.x >> 6, lane = threadIdx.x & 63, quad = lane >> 4, l16 = lane & 15;
    int m0 = blockIdx.x * 64 + wave * 16;
    int n0 = blockIdx.y * 64;
    int bh = blockIdx.z;
    const unsigned short* qb = q + (long long)bh * 1024 * 32;
    const unsigned short* kb = k + (long long)bh * 1024 * 32;
    bf16x8 a = *reinterpret_cast<const bf16x8*>(qb + (m0 + l16) * 32 + quad * 8);
    f32x4 acc[4] = {};
#pragma unroll
    for (int ni = 0; ni < 4; ni++) {
        bf16x8 bv = *reinterpret_cast<const bf16x8*>(kb + (n0 + ni * 16 + l16) * 32 + quad * 8);
        acc[ni] = MFMA16(a, bv, acc[ni]);
    }
    int h = bh & 7;
    const float scale = 0.17677669529663687f;  // 1/sqrt(32)
    float* Sb = S + (long long)bh * 1024 * 1024;
#pragma unroll
    for (int ni = 0; ni < 4; ni++) {
        int kj = n0 + ni * 16 + l16;
        int kj0 = kj >> 5, kj1 = kj & 31;
#pragma unroll
        for (int r = 0; r < 4; r++) {
            int qi = m0 + quad * 4 + r;
            int qi0 = qi >> 5, qi1 = qi & 31;
            int idx = (qi0 - kj0 + 31) * 63 + (qi1 - kj1 + 31);
            Sb[(long long)qi * 1024 + kj] = acc[ni][r] * scale + rpe[idx * 8 + h];
        }
    }
}

// ---------------- row softmax over 1024, one wave per row -> bf16 P ----------------
__global__ __launch_bounds__(256) void k_softmax(const float* __restrict__ S,
                                                 unsigned short* __restrict__ P) {
    int wave = threadIdx.x >> 6, lane = threadIdx.x & 63;
    long long row = (long long)blockIdx.x * 4 + wave;
    const float* s = S + row * 1024;
    float4 v[4];
    float mx = -3.4e38f;
#pragma unroll
    for (int i = 0; i < 4; i++) {
        v[i] = *reinterpret_cast<const float4*>(s + i * 256 + lane * 4);
        mx = fmaxf(mx, fmaxf(fmaxf(v[i].x, v[i].y), fmaxf(v[i].z, v[i].w)));
    }
    mx = wave_max(mx);
    float sum = 0.f;
#pragma unroll
    for (int i = 0; i < 4; i++) {
        v[i].x = __expf(v[i].x - mx); v[i].y = __expf(v[i].y - mx);
        v[i].z = __expf(v[i].z - mx); v[i].w = __expf(v[i].w - mx);
        sum += v[i].x + v[i].y + v[i].z + v[i].w;
    }
    sum = wave_sum(sum);
    float inv = 1.f / sum;
#pragma unroll
    for (int i = 0; i < 4; i++) {
        ushort4 o;
        o.x = f2bf(v[i].x * inv); o.y = f2bf(v[i].y * inv);
        o.z = f2bf(v[i].z * inv); o.w = f2bf(v[i].w * inv);
        *reinterpret_cast<ushort4*>(P + row * 1024 + i * 256 + lane * 4) = o;
    }
}

// ---------------- O = P@V per (b,h), K=1024 -> token-major obf ----------------
__global__ __launch_bounds__(256) void k_pv(const unsigned short* __restrict__ P,
                                            const unsigned short* __restrict__ vT,
                                            unsigned short* __restrict__ o) {
    int wave = threadIdx.x >> 6, lane = threadIdx.x & 63, quad = lane >> 4, l16 = lane & 15;
    int m0 = blockIdx.x * 64 + wave * 16;
    int bh = blockIdx.y;
    const unsigned short* Pb = P + (long long)bh * 1024 * 1024;
    const unsigned short* vb = vT + (long long)bh * 32 * 1024;
    f32x4 acc[2] = {};
    for (int kb = 0; kb < 1024; kb += 32) {
        bf16x8 a = *reinterpret_cast<const bf16x8*>(Pb + (long long)(m0 + l16) * 1024 + kb + quad * 8);
#pragma unroll
        for (int ni = 0; ni < 2; ni++) {
            bf16x8 bv = *reinterpret_cast<const bf16x8*>(vb + (long long)(ni * 16 + l16) * 1024 + kb + quad * 8);
            acc[ni] = MFMA16(a, bv, acc[ni]);
        }
    }
    int b_ = bh >> 3, h = bh & 7;
#pragma unroll
    for (int ni = 0; ni < 2; ni++) {
        int d = ni * 16 + l16;
#pragma unroll
        for (int r = 0; r < 4; r++) {
            int l = m0 + quad * 4 + r;
            o[(long long)(b_ * 1024 + l) * 256 + h * 32 + d] = f2bf(acc[ni][r]);
        }
    }
}

// ---------------- proj: [2048,256]x[256,256]^T -> bf16 ----------------
__global__ __launch_bounds__(256) void k_gemm_proj(const unsigned short* __restrict__ a_,
                                                   const unsigned short* __restrict__ w,
                                                   const float* __restrict__ bias,
                                                   unsigned short* __restrict__ y) {
    int wave = threadIdx.x >> 6, lane = threadIdx.x & 63, quad = lane >> 4, l16 = lane & 15;
    int m0 = blockIdx.x * 64 + wave * 16;
    int n0 = blockIdx.y * 64;
    const unsigned short* arow = a_ + (long long)(m0 + l16) * 256;
    f32x4 acc[4] = {};
    for (int kb = 0; kb < 256; kb += 32) {
        bf16x8 a = *reinterpret_cast<const bf16x8*>(arow + kb + quad * 8);
#pragma unroll
        for (int ni = 0; ni < 4; ni++) {
            bf16x8 bv = *reinterpret_cast<const bf16x8*>(w + (long long)(n0 + ni * 16 + l16) * 256 + kb + quad * 8);
            acc[ni] = MFMA16(a, bv, acc[ni]);
        }
    }
#pragma unroll
    for (int ni = 0; ni < 4; ni++) {
        int n = n0 + ni * 16 + l16;
        float bv = bias[n];
#pragma unroll
        for (int r = 0; r < 4; r++)
            y[(long long)(m0 + quad * 4 + r) * 256 + n] = f2bf(acc[ni][r] + bv);
    }
}

// ---------------- up-proj + fold + residual: x2 = x + fold(oproj @ w_up^T + b_up) ----------------
__global__ __launch_bounds__(256) void k_up_fold(const unsigned short* __restrict__ a_,
                                                 const unsigned short* __restrict__ w,
                                                 const float* __restrict__ bup,
                                                 const float* __restrict__ x,
                                                 float* __restrict__ out) {
    int wave = threadIdx.x >> 6, lane = threadIdx.x & 63, quad = lane >> 4, l16 = lane & 15;
    int m0 = blockIdx.x * 64 + wave * 16;
    int n0 = blockIdx.y * 64;
    const unsigned short* arow = a_ + (long long)(m0 + l16) * 256;
    f32x4 acc[4] = {};
    for (int kb = 0; kb < 256; kb += 32) {
        bf16x8 a = *reinterpret_cast<const bf16x8*>(arow + kb + quad * 8);
#pragma unroll
        for (int ni = 0; ni < 4; ni++) {
            bf16x8 bv = *reinterpret_cast<const bf16x8*>(w + (long long)(n0 + ni * 16 + l16) * 256 + kb + quad * 8);
            acc[ni] = MFMA16(a, bv, acc[ni]);
        }
    }
#pragma unroll
    for (int ni = 0; ni < 4; ni++) {
        int n = n0 + ni * 16 + l16;
        float bias = bup[n];
        int p0 = n >> 11, p1 = (n >> 8) & 7, c = n & 255;
#pragma unroll
        for (int r = 0; r < 4; r++) {
            int m = m0 + quad * 4 + r;
            int bb = m >> 10, r0 = (m >> 5) & 31, r1 = m & 31;
            long long addr = ((long long)bb << 24) + (long long)(r0 * 8 + p0) * 65536 + (r1 * 8 + p1) * 256 + c;
            out[addr] = x[addr] + acc[ni][r] + bias;
        }
    }
}

// ---------------- fused LN2 + MLP + residual, in-place on d_out ----------------
#define LP 264  // 256 + 8 pad: row stride 528 B -> bank step 4, 2-way max (free)
__global__ __launch_bounds__(256, 2) void k_mlp(float* __restrict__ xio,
                                                const float* __restrict__ g2,
                                                const float* __restrict__ b2,
                                                const unsigned short* __restrict__ w1,
                                                const float* __restrict__ bfc1,
                                                const unsigned short* __restrict__ w2,
                                                const float* __restrict__ bfc2) {
    __shared__ unsigned short Aln[64 * LP];
    __shared__ unsigned short Hc[64 * LP];
    int wave = threadIdx.x >> 6, lane = threadIdx.x & 63, quad = lane >> 4, l16 = lane & 15;
    long long m0 = (long long)blockIdx.x * 64;
    float4 gg = *reinterpret_cast<const float4*>(g2 + lane * 4);
    float4 bb = *reinterpret_cast<const float4*>(b2 + lane * 4);
    for (int i = 0; i < 16; i++) {
        int p = wave * 16 + i;
        float4 v = *reinterpret_cast<const float4*>(xio + (m0 + p) * 256 + lane * 4);
        float s = v.x + v.y + v.z + v.w;
        float s2 = v.x * v.x + v.y * v.y + v.z * v.z + v.w * v.w;
        s = wave_sum(s); s2 = wave_sum(s2);
        float mean = s * (1.f / 256.f);
        float rstd = rsqrtf(s2 * (1.f / 256.f) - mean * mean + 1e-5f);
        ushort4 o;
        o.x = f2bf((v.x - mean) * rstd * gg.x + bb.x);
        o.y = f2bf((v.y - mean) * rstd * gg.y + bb.y);
        o.z = f2bf((v.z - mean) * rstd * gg.z + bb.z);
        o.w = f2bf((v.w - mean) * rstd * gg.w + bb.w);
        *reinterpret_cast<ushort4*>(&Aln[p * LP + lane * 4]) = o;
    }
    __syncthreads();
    f32x4 acc2[4][4] = {};
    for (int ch = 0; ch < 4; ch++) {
        f32x4 acc1[4][4] = {};
        for (int kb = 0; kb < 256; kb += 32) {
            bf16x8 af[4];
#pragma unroll
            for (int mi = 0; mi < 4; mi++)
                af[mi] = *reinterpret_cast<const bf16x8*>(&Aln[(mi * 16 + l16) * LP + kb + quad * 8]);
#pragma unroll
            for (int ni = 0; ni < 4; ni++) {
                bf16x8 bv = *reinterpret_cast<const bf16x8*>(w1 + (long long)(ch * 256 + wave * 64 + ni * 16 + l16) * 256 + kb + quad * 8);
#pragma unroll
                for (int mi = 0; mi < 4; mi++)
                    acc1[mi][ni] = MFMA16(af[mi], bv, acc1[mi][ni]);
            }
        }
#pragma unroll
        for (int ni = 0; ni < 4; ni++) {
            int n = ch * 256 + wave * 64 + ni * 16 + l16;
            float bias = bfc1[n];
            int col = wave * 64 + ni * 16 + l16;
#pragma unroll
            for (int mi = 0; mi < 4; mi++) {
#pragma unroll
                for (int r = 0; r < 4; r++) {
                    float vv = acc1[mi][ni][r] + bias;
                    vv = 0.5f * vv * (1.f + erff(vv * 0.70710678118f));
                    Hc[(mi * 16 + quad * 4 + r) * LP + col] = f2bf(vv);
                }
            }
        }
        __syncthreads();
        for (int kb = 0; kb < 256; kb += 32) {
            bf16x8 af[4];
#pragma unroll
            for (int mi = 0; mi < 4; mi++)
                af[mi] = *reinterpret_cast<const bf16x8*>(&Hc[(mi * 16 + l16) * LP + kb + quad * 8]);
#pragma unroll
            for (int ni = 0; ni < 4; ni++) {
                bf16x8 bv = *reinterpret_cast<const bf16x8*>(w2 + (long long)(wave * 64 + ni * 16 + l16) * 1024 + ch * 256 + kb + quad * 8);
#pragma unroll
                for (int mi = 0; mi < 4; mi++)
                    acc2[mi][ni] = MFMA16(af[mi], bv, acc2[mi][ni]);
            }
        }
        __syncthreads();
    }
#pragma unroll
    for (int ni = 0; ni < 4; ni++) {
        int n = wave * 64 + ni * 16 + l16;
        float bias = bfc2[n];
#pragma unroll
        for (int mi = 0; mi < 4; mi++) {
#pragma unroll
            for (int r = 0; r < 4; r++) {
                long long row = m0 + mi * 16 + quad * 4 + r;
                float xv = xio[row * 256 + n];
                xio[row * 256 + n] = xv + acc2[mi][ni][r] + bias;
            }
        }
    }
}

extern "C" void kernel_launch(void* const* d_in, const int* in_sizes, int n_in,
                              void* d_out, int out_size, void* d_ws, size_t ws_size,
                              hipStream_t stream) {
    const float* x      = (const float*)d_in[0];
    const float* ln1_g  = (const float*)d_in[1];
    const float* ln1_b  = (const float*)d_in[2];
    const float* ln2_g  = (const float*)d_in[3];
    const float* ln2_b  = (const float*)d_in[4];
    const float* rpe    = (const float*)d_in[5];
    const float* w_down = (const float*)d_in[6];
    const float* b_down = (const float*)d_in[7];
    const float* w_up   = (const float*)d_in[8];
    const float* b_up   = (const float*)d_in[9];
    const float* w_qkv  = (const float*)d_in[10];
    const float* b_qkv  = (const float*)d_in[11];
    const float* w_proj = (const float*)d_in[12];
    const float* b_proj = (const float*)d_in[13];
    const float* w_fc1  = (const float*)d_in[14];
    const float* b_fc1  = (const float*)d_in[15];
    const float* w_fc2  = (const float*)d_in[16];
    const float* b_fc2  = (const float*)d_in[17];
    float* out = (float*)d_out;

    char* wp = (char*)d_ws;
    auto alloc = [&](size_t bytes) { void* p = (void*)wp; wp += (bytes + 255) & ~(size_t)255; return p; };
    unsigned short* wdown_bf = (unsigned short*)alloc(4194304 * 2);
    unsigned short* wup_bf   = (unsigned short*)alloc(4194304 * 2);
    unsigned short* wqkv_bf  = (unsigned short*)alloc(196608 * 2);
    unsigned short* wproj_bf = (unsigned short*)alloc(65536 * 2);
    unsigned short* wfc1_bf  = (unsigned short*)alloc(262144 * 2);
    unsigned short* wfc2_bf  = (unsigned short*)alloc(262144 * 2);
    unsigned short* ydown    = (unsigned short*)alloc(524288 * 2);
    unsigned short* qb       = (unsigned short*)alloc(524288 * 2);
    unsigned short* kb       = (unsigned short*)alloc(524288 * 2);
    unsigned short* vT       = (unsigned short*)alloc(524288 * 2);
    unsigned short* obf      = (unsigned short*)alloc(524288 * 2);
    unsigned short* oproj    = (unsigned short*)alloc(524288 * 2);

    // Big temporaries live inside d_out (134 MB); all dead before k_up_fold
    // overwrites the whole buffer with x2. xln and S alias (disjoint lifetimes).
    unsigned short* xln = (unsigned short*)d_out;                         // 67 MB
    float* S            = (float*)d_out;                                  // 67 MB
    unsigned short* P   = (unsigned short*)((char*)d_out + 67108864);     // 33.5 MB

    k_cvt<<<4096, 256, 0, stream>>>(w_down, wdown_bf, 4194304);
    k_cvt<<<4096, 256, 0, stream>>>(w_up, wup_bf, 4194304);
    k_cvt<<<192, 256, 0, stream>>>(w_qkv, wqkv_bf, 196608);
    k_cvt<<<64, 256, 0, stream>>>(w_proj, wproj_bf, 65536);
    k_cvt<<<256, 256, 0, stream>>>(w_fc1, wfc1_bf, 262144);
    k_cvt<<<256, 256, 0, stream>>>(w_fc2, wfc2_bf, 262144);

    k_ln_bf<<<32768, 256, 0, stream>>>(x, ln1_g, ln1_b, xln);
    k_gemm_down<<<dim3(32, 4), 256, 0, stream>>>(xln, wdown_bf, b_down, ydown);
    k_gemm_qkv<<<dim3(32, 12), 256, 0, stream>>>(ydown, wqkv_bf, b_qkv, qb, kb, vT);
    k_score<<<dim3(16, 16, 16), 256, 0, stream>>>(qb, kb, rpe, S);
    k_softmax<<<4096, 256, 0, stream>>>(S, P);
    k_pv<<<dim3(16, 16), 256, 0, stream>>>(P, vT, obf);
    k_gemm_proj<<<dim3(32, 4), 256, 0, stream>>>(obf, wproj_bf, b_proj, oproj);
    k_up_fold<<<dim3(32, 256), 256, 0, stream>>>(oproj, wup_bf, b_up, x, out);
    k_mlp<<<2048, 256, 0, stream>>>(out, ln2_g, ln2_b, wfc1_bf, b_fc1, wfc2_bf, b_fc2);
}

// Round 2
// 909.147 us; speedup vs baseline: 1.4126x; 1.4126x over previous
//
#include <hip/hip_runtime.h>

typedef __attribute__((ext_vector_type(8))) __bf16 bf16x8;
typedef __attribute__((ext_vector_type(4))) float f32x4;

#define MFMA16(a, b, c) __builtin_amdgcn_mfma_f32_16x16x32_bf16((a), (b), (c), 0, 0, 0)

// async global->LDS, 16B per lane; LDS dest = wave-uniform base + lane*16
#define ASYNC16(g, l) __builtin_amdgcn_global_load_lds( \
    (const __attribute__((address_space(1))) unsigned int*)(g), \
    (__attribute__((address_space(3))) unsigned int*)(l), 16, 0, 0)

__device__ __forceinline__ unsigned short f2bf(float f) {
    unsigned int u = __builtin_bit_cast(unsigned int, f);
    u += 0x7fffu + ((u >> 16) & 1u);
    return (unsigned short)(u >> 16);
}

__device__ __forceinline__ float wave_sum(float v) {
#pragma unroll
    for (int off = 32; off; off >>= 1) v += __shfl_xor(v, off, 64);
    return v;
}
__device__ __forceinline__ float wave_max(float v) {
#pragma unroll
    for (int off = 32; off; off >>= 1) v = fmaxf(v, __shfl_xor(v, off, 64));
    return v;
}

// ---------------- fp32 -> bf16 cast (weights) ----------------
__global__ __launch_bounds__(256) void k_cvt(const float* __restrict__ s,
                                             unsigned short* __restrict__ d, int n) {
    int i = (blockIdx.x * 256 + threadIdx.x) * 4;
    if (i >= n) return;
    float4 v = *reinterpret_cast<const float4*>(s + i);
    ushort4 o;
    o.x = f2bf(v.x); o.y = f2bf(v.y); o.z = f2bf(v.z); o.w = f2bf(v.w);
    *reinterpret_cast<ushort4*>(d + i) = o;
}

// ---------------- LN1 over C=256, one wave per pixel -> bf16 ----------------
__global__ __launch_bounds__(256) void k_ln_bf(const float* __restrict__ x,
                                               const float* __restrict__ g,
                                               const float* __restrict__ b,
                                               unsigned short* __restrict__ o) {
    int wave = threadIdx.x >> 6, lane = threadIdx.x & 63;
    long long pix = (long long)blockIdx.x * 4 + wave;
    const float* row = x + pix * 256;
    float4 v = *reinterpret_cast<const float4*>(row + lane * 4);
    float s = v.x + v.y + v.z + v.w;
    float s2 = v.x * v.x + v.y * v.y + v.z * v.z + v.w * v.w;
    s = wave_sum(s); s2 = wave_sum(s2);
    float mean = s * (1.f / 256.f);
    float rstd = rsqrtf(s2 * (1.f / 256.f) - mean * mean + 1e-5f);
    float4 gg = *reinterpret_cast<const float4*>(g + lane * 4);
    float4 bb = *reinterpret_cast<const float4*>(b + lane * 4);
    ushort4 ov;
    ov.x = f2bf((v.x - mean) * rstd * gg.x + bb.x);
    ov.y = f2bf((v.y - mean) * rstd * gg.y + bb.y);
    ov.z = f2bf((v.z - mean) * rstd * gg.z + bb.z);
    ov.w = f2bf((v.w - mean) * rstd * gg.w + bb.w);
    *reinterpret_cast<ushort4*>(o + pix * 256 + lane * 4) = ov;
}

// ---------------- down-proj v2: split-K(16) 128x128 LDS-staged MFMA GEMM ----------------
// grid (16, 2, 16); A addressed through the unfold permutation; XOR chunk swizzle
// breaks the 16-way LDS bank conflict (row stride = 128B = exactly 32 banks).
__global__ __launch_bounds__(256, 2) void k_gemm_down2(const unsigned short* __restrict__ xln,
                                                       const unsigned short* __restrict__ wd,
                                                       float* __restrict__ part) {
    __shared__ alignas(16) unsigned short As[128 * 64];
    __shared__ alignas(16) unsigned short Bs[128 * 64];
    int wave = threadIdx.x >> 6, lane = threadIdx.x & 63, quad = lane >> 4, l16 = lane & 15;
    int mt = blockIdx.x * 128, nt = blockIdx.y * 128, k0 = blockIdx.z * 1024;
    int wm = wave & 1, wn = wave >> 1;
    int srow = wave * 32 + (lane >> 3);   // staging row (+ i*8)
    int schunk = lane & 7;                // 16B chunk within 128B row
    f32x4 acc[4][4] = {};
    for (int s = 0; s < 16; s++) {
        int kg = k0 + s * 64;
        int p0 = kg >> 11, p1 = (kg >> 8) & 7, cbase = kg & 255;
#pragma unroll
        for (int i = 0; i < 4; i++) {
            int row = srow + i * 8;
            int m = mt + row;
            int bb = m >> 10, r0 = (m >> 5) & 31, r1 = m & 31;
            int c = cbase + ((schunk ^ (row & 7)) << 3);
            const unsigned short* g = xln +
                ((((long long)(bb * 256 + r0 * 8 + p0)) * 256 + (r1 * 8 + p1)) << 8) + c;
            ASYNC16(g, &As[(wave * 32 + i * 8) * 64]);
        }
#pragma unroll
        for (int i = 0; i < 4; i++) {
            int row = srow + i * 8;
            int n = nt + row;
            const unsigned short* g = wd + (long long)n * 16384 + kg + ((schunk ^ (row & 7)) << 3);
            ASYNC16(g, &Bs[(wave * 32 + i * 8) * 64]);
        }
        __syncthreads();
#pragma unroll
        for (int sub = 0; sub < 2; sub++) {
            int c = sub * 4 + quad;
            bf16x8 af[4], bfr[4];
#pragma unroll
            for (int mi = 0; mi < 4; mi++) {
                int row = wm * 64 + mi * 16 + l16;
                af[mi] = *reinterpret_cast<const bf16x8*>(&As[row * 64 + ((c ^ (row & 7)) << 3)]);
            }
#pragma unroll
            for (int ni = 0; ni < 4; ni++) {
                int row = wn * 64 + ni * 16 + l16;
                bfr[ni] = *reinterpret_cast<const bf16x8*>(&Bs[row * 64 + ((c ^ (row & 7)) << 3)]);
            }
#pragma unroll
            for (int mi = 0; mi < 4; mi++)
#pragma unroll
                for (int ni = 0; ni < 4; ni++)
                    acc[mi][ni] = MFMA16(af[mi], bfr[ni], acc[mi][ni]);
        }
        __syncthreads();
    }
    float* pb = part + (long long)blockIdx.z * 524288;
#pragma unroll
    for (int mi = 0; mi < 4; mi++)
#pragma unroll
        for (int ni = 0; ni < 4; ni++) {
            int n = nt + wn * 64 + ni * 16 + l16;
#pragma unroll
            for (int r = 0; r < 4; r++) {
                int m = mt + wm * 64 + mi * 16 + quad * 4 + r;
                pb[(long long)m * 256 + n] = acc[mi][ni][r];
            }
        }
}

// ---------------- split-K reduce + bias + bf16 ----------------
__global__ __launch_bounds__(256) void k_red(const float* __restrict__ part,
                                             const float* __restrict__ bd,
                                             unsigned short* __restrict__ y) {
    int i = (blockIdx.x * 256 + threadIdx.x) * 4;
    float4 s = {0.f, 0.f, 0.f, 0.f};
#pragma unroll
    for (int p = 0; p < 16; p++) {
        float4 v = *reinterpret_cast<const float4*>(part + (long long)p * 524288 + i);
        s.x += v.x; s.y += v.y; s.z += v.z; s.w += v.w;
    }
    int n = i & 255;
    float4 bb = *reinterpret_cast<const float4*>(bd + n);
    ushort4 o;
    o.x = f2bf(s.x + bb.x); o.y = f2bf(s.y + bb.y);
    o.z = f2bf(s.z + bb.z); o.w = f2bf(s.w + bb.w);
    *reinterpret_cast<ushort4*>(y + i) = o;
}

// ---------------- qkv: [2048,256]x[768,256]^T, scatter to q, k, v^T (bf16) ----------------
__global__ __launch_bounds__(256) void k_gemm_qkv(const unsigned short* __restrict__ yd,
                                                  const unsigned short* __restrict__ wq,
                                                  const float* __restrict__ bq,
                                                  unsigned short* __restrict__ q,
                                                  unsigned short* __restrict__ k,
                                                  unsigned short* __restrict__ vT) {
    int wave = threadIdx.x >> 6, lane = threadIdx.x & 63, quad = lane >> 4, l16 = lane & 15;
    int m0 = blockIdx.x * 64 + wave * 16;
    int n0 = blockIdx.y * 64;
    const unsigned short* arow = yd + (long long)(m0 + l16) * 256;
    f32x4 acc[4] = {};
    for (int kb = 0; kb < 256; kb += 32) {
        bf16x8 a = *reinterpret_cast<const bf16x8*>(arow + kb + quad * 8);
#pragma unroll
        for (int ni = 0; ni < 4; ni++) {
            bf16x8 bv = *reinterpret_cast<const bf16x8*>(wq + (long long)(n0 + ni * 16 + l16) * 256 + kb + quad * 8);
            acc[ni] = MFMA16(a, bv, acc[ni]);
        }
    }
#pragma unroll
    for (int ni = 0; ni < 4; ni++) {
        int n = n0 + ni * 16 + l16;
        float bias = bq[n];
        int t = n >> 8, h = (n >> 5) & 7, d = n & 31;
#pragma unroll
        for (int r = 0; r < 4; r++) {
            int m = m0 + quad * 4 + r;
            int bh = ((m >> 10) << 3) | h;
            int l = m & 1023;
            unsigned short val = f2bf(acc[ni][r] + bias);
            if (t == 0)      q[((long long)bh * 1024 + l) * 32 + d] = val;
            else if (t == 1) k[((long long)bh * 1024 + l) * 32 + d] = val;
            else             vT[((long long)bh * 32 + d) * 1024 + l] = val;
        }
    }
}

// ---------------- scores: S = scale*q@k^T + rpe (fp32) ----------------
__global__ __launch_bounds__(256) void k_score(const unsigned short* __restrict__ q,
                                               const unsigned short* __restrict__ k,
                                               const float* __restrict__ rpe,
                                               float* __restrict__ S) {
    int wave = threadIdx.x >> 6, lane = threadIdx.x & 63, quad = lane >> 4, l16 = lane & 15;
    int m0 = blockIdx.x * 64 + wave * 16;
    int n0 = blockIdx.y * 64;
    int bh = blockIdx.z;
    const unsigned short* qb = q + (long long)bh * 1024 * 32;
    const unsigned short* kb = k + (long long)bh * 1024 * 32;
    bf16x8 a = *reinterpret_cast<const bf16x8*>(qb + (m0 + l16) * 32 + quad * 8);
    f32x4 acc[4] = {};
#pragma unroll
    for (int ni = 0; ni < 4; ni++) {
        bf16x8 bv = *reinterpret_cast<const bf16x8*>(kb + (n0 + ni * 16 + l16) * 32 + quad * 8);
        acc[ni] = MFMA16(a, bv, acc[ni]);
    }
    int h = bh & 7;
    const float scale = 0.17677669529663687f;  // 1/sqrt(32)
    float* Sb = S + (long long)bh * 1024 * 1024;
#pragma unroll
    for (int ni = 0; ni < 4; ni++) {
        int kj = n0 + ni * 16 + l16;
        int kj0 = kj >> 5, kj1 = kj & 31;
#pragma unroll
        for (int r = 0; r < 4; r++) {
            int qi = m0 + quad * 4 + r;
            int qi0 = qi >> 5, qi1 = qi & 31;
            int idx = (qi0 - kj0 + 31) * 63 + (qi1 - kj1 + 31);
            Sb[(long long)qi * 1024 + kj] = acc[ni][r] * scale + rpe[idx * 8 + h];
        }
    }
}

// ---------------- row softmax over 1024, one wave per row -> bf16 P ----------------
__global__ __launch_bounds__(256) void k_softmax(const float* __restrict__ S,
                                                 unsigned short* __restrict__ P) {
    int wave = threadIdx.x >> 6, lane = threadIdx.x & 63;
    long long row = (long long)blockIdx.x * 4 + wave;
    const float* s = S + row * 1024;
    float4 v[4];
    float mx = -3.4e38f;
#pragma unroll
    for (int i = 0; i < 4; i++) {
        v[i] = *reinterpret_cast<const float4*>(s + i * 256 + lane * 4);
        mx = fmaxf(mx, fmaxf(fmaxf(v[i].x, v[i].y), fmaxf(v[i].z, v[i].w)));
    }
    mx = wave_max(mx);
    float sum = 0.f;
#pragma unroll
    for (int i = 0; i < 4; i++) {
        v[i].x = __expf(v[i].x - mx); v[i].y = __expf(v[i].y - mx);
        v[i].z = __expf(v[i].z - mx); v[i].w = __expf(v[i].w - mx);
        sum += v[i].x + v[i].y + v[i].z + v[i].w;
    }
    sum = wave_sum(sum);
    float inv = 1.f / sum;
#pragma unroll
    for (int i = 0; i < 4; i++) {
        ushort4 o;
        o.x = f2bf(v[i].x * inv); o.y = f2bf(v[i].y * inv);
        o.z = f2bf(v[i].z * inv); o.w = f2bf(v[i].w * inv);
        *reinterpret_cast<ushort4*>(P + row * 1024 + i * 256 + lane * 4) = o;
    }
}

// ---------------- O = P@V per (b,h), K=1024 -> token-major obf ----------------
__global__ __launch_bounds__(256) void k_pv(const unsigned short* __restrict__ P,
                                            const unsigned short* __restrict__ vT,
                                            unsigned short* __restrict__ o) {
    int wave = threadIdx.x >> 6, lane = threadIdx.x & 63, quad = lane >> 4, l16 = lane & 15;
    int m0 = blockIdx.x * 64 + wave * 16;
    int bh = blockIdx.y;
    const unsigned short* Pb = P + (long long)bh * 1024 * 1024;
    const unsigned short* vb = vT + (long long)bh * 32 * 1024;
    f32x4 acc[2] = {};
    for (int kb = 0; kb < 1024; kb += 32) {
        bf16x8 a = *reinterpret_cast<const bf16x8*>(Pb + (long long)(m0 + l16) * 1024 + kb + quad * 8);
#pragma unroll
        for (int ni = 0; ni < 2; ni++) {
            bf16x8 bv = *reinterpret_cast<const bf16x8*>(vb + (long long)(ni * 16 + l16) * 1024 + kb + quad * 8);
            acc[ni] = MFMA16(a, bv, acc[ni]);
        }
    }
    int b_ = bh >> 3, h = bh & 7;
#pragma unroll
    for (int ni = 0; ni < 2; ni++) {
        int d = ni * 16 + l16;
#pragma unroll
        for (int r = 0; r < 4; r++) {
            int l = m0 + quad * 4 + r;
            o[(long long)(b_ * 1024 + l) * 256 + h * 32 + d] = f2bf(acc[ni][r]);
        }
    }
}

// ---------------- proj: [2048,256]x[256,256]^T -> bf16 ----------------
__global__ __launch_bounds__(256) void k_gemm_proj(const unsigned short* __restrict__ a_,
                                                   const unsigned short* __restrict__ w,
                                                   const float* __restrict__ bias,
                                                   unsigned short* __restrict__ y) {
    int wave = threadIdx.x >> 6, lane = threadIdx.x & 63, quad = lane >> 4, l16 = lane & 15;
    int m0 = blockIdx.x * 64 + wave * 16;
    int n0 = blockIdx.y * 64;
    const unsigned short* arow = a_ + (long long)(m0 + l16) * 256;
    f32x4 acc[4] = {};
    for (int kb = 0; kb < 256; kb += 32) {
        bf16x8 a = *reinterpret_cast<const bf16x8*>(arow + kb + quad * 8);
#pragma unroll
        for (int ni = 0; ni < 4; ni++) {
            bf16x8 bv = *reinterpret_cast<const bf16x8*>(w + (long long)(n0 + ni * 16 + l16) * 256 + kb + quad * 8);
            acc[ni] = MFMA16(a, bv, acc[ni]);
        }
    }
#pragma unroll
    for (int ni = 0; ni < 4; ni++) {
        int n = n0 + ni * 16 + l16;
        float bv = bias[n];
#pragma unroll
        for (int r = 0; r < 4; r++)
            y[(long long)(m0 + quad * 4 + r) * 256 + n] = f2bf(acc[ni][r] + bv);
    }
}

// ---------------- up-proj + fold + residual: x2 = x + fold(oproj @ w_up^T + b_up) ----------------
__global__ __launch_bounds__(256) void k_up_fold(const unsigned short* __restrict__ a_,
                                                 const unsigned short* __restrict__ w,
                                                 const float* __restrict__ bup,
                                                 const float* __restrict__ x,
                                                 float* __restrict__ out) {
    int wave = threadIdx.x >> 6, lane = threadIdx.x & 63, quad = lane >> 4, l16 = lane & 15;
    int m0 = blockIdx.x * 64 + wave * 16;
    int n0 = blockIdx.y * 64;
    const unsigned short* arow = a_ + (long long)(m0 + l16) * 256;
    f32x4 acc[4] = {};
    for (int kb = 0; kb < 256; kb += 32) {
        bf16x8 a = *reinterpret_cast<const bf16x8*>(arow + kb + quad * 8);
#pragma unroll
        for (int ni = 0; ni < 4; ni++) {
            bf16x8 bv = *reinterpret_cast<const bf16x8*>(w + (long long)(n0 + ni * 16 + l16) * 256 + kb + quad * 8);
            acc[ni] = MFMA16(a, bv, acc[ni]);
        }
    }
#pragma unroll
    for (int ni = 0; ni < 4; ni++) {
        int n = n0 + ni * 16 + l16;
        float bias = bup[n];
        int p0 = n >> 11, p1 = (n >> 8) & 7, c = n & 255;
#pragma unroll
        for (int r = 0; r < 4; r++) {
            int m = m0 + quad * 4 + r;
            int bb = m >> 10, r0 = (m >> 5) & 31, r1 = m & 31;
            long long addr = ((long long)bb << 24) + (long long)(r0 * 8 + p0) * 65536 + (r1 * 8 + p1) * 256 + c;
            out[addr] = x[addr] + acc[ni][r] + bias;
        }
    }
}

// ---------------- fused LN2 + MLP + residual, in-place on d_out ----------------
#define LP 264  // 256 + 8 pad: row stride 528 B -> bank step 4, 2-way max (free)
__global__ __launch_bounds__(256, 2) void k_mlp(float* __restrict__ xio,
                                                const float* __restrict__ g2,
                                                const float* __restrict__ b2,
                                                const unsigned short* __restrict__ w1,
                                                const float* __restrict__ bfc1,
                                                const unsigned short* __restrict__ w2,
                                                const float* __restrict__ bfc2) {
    __shared__ unsigned short Aln[64 * LP];
    __shared__ unsigned short Hc[64 * LP];
    int wave = threadIdx.x >> 6, lane = threadIdx.x & 63, quad = lane >> 4, l16 = lane & 15;
    long long m0 = (long long)blockIdx.x * 64;
    float4 gg = *reinterpret_cast<const float4*>(g2 + lane * 4);
    float4 bb = *reinterpret_cast<const float4*>(b2 + lane * 4);
    for (int i = 0; i < 16; i++) {
        int p = wave * 16 + i;
        float4 v = *reinterpret_cast<const float4*>(xio + (m0 + p) * 256 + lane * 4);
        float s = v.x + v.y + v.z + v.w;
        float s2 = v.x * v.x + v.y * v.y + v.z * v.z + v.w * v.w;
        s = wave_sum(s); s2 = wave_sum(s2);
        float mean = s * (1.f / 256.f);
        float rstd = rsqrtf(s2 * (1.f / 256.f) - mean * mean + 1e-5f);
        ushort4 o;
        o.x = f2bf((v.x - mean) * rstd * gg.x + bb.x);
        o.y = f2bf((v.y - mean) * rstd * gg.y + bb.y);
        o.z = f2bf((v.z - mean) * rstd * gg.z + bb.z);
        o.w = f2bf((v.w - mean) * rstd * gg.w + bb.w);
        *reinterpret_cast<ushort4*>(&Aln[p * LP + lane * 4]) = o;
    }
    __syncthreads();
    f32x4 acc2[4][4] = {};
    for (int ch = 0; ch < 4; ch++) {
        f32x4 acc1[4][4] = {};
        for (int kb = 0; kb < 256; kb += 32) {
            bf16x8 af[4];
#pragma unroll
            for (int mi = 0; mi < 4; mi++)
                af[mi] = *reinterpret_cast<const bf16x8*>(&Aln[(mi * 16 + l16) * LP + kb + quad * 8]);
#pragma unroll
            for (int ni = 0; ni < 4; ni++) {
                bf16x8 bv = *reinterpret_cast<const bf16x8*>(w1 + (long long)(ch * 256 + wave * 64 + ni * 16 + l16) * 256 + kb + quad * 8);
#pragma unroll
                for (int mi = 0; mi < 4; mi++)
                    acc1[mi][ni] = MFMA16(af[mi], bv, acc1[mi][ni]);
            }
        }
#pragma unroll
        for (int ni = 0; ni < 4; ni++) {
            int n = ch * 256 + wave * 64 + ni * 16 + l16;
            float bias = bfc1[n];
            int col = wave * 64 + ni * 16 + l16;
#pragma unroll
            for (int mi = 0; mi < 4; mi++) {
#pragma unroll
                for (int r = 0; r < 4; r++) {
                    float vv = acc1[mi][ni][r] + bias;
                    vv = 0.5f * vv * (1.f + erff(vv * 0.70710678118f));
                    Hc[(mi * 16 + quad * 4 + r) * LP + col] = f2bf(vv);
                }
            }
        }
        __syncthreads();
        for (int kb = 0; kb < 256; kb += 32) {
            bf16x8 af[4];
#pragma unroll
            for (int mi = 0; mi < 4; mi++)
                af[mi] = *reinterpret_cast<const bf16x8*>(&Hc[(mi * 16 + l16) * LP + kb + quad * 8]);
#pragma unroll
            for (int ni = 0; ni < 4; ni++) {
                bf16x8 bv = *reinterpret_cast<const bf16x8*>(w2 + (long long)(wave * 64 + ni * 16 + l16) * 1024 + ch * 256 + kb + quad * 8);
#pragma unroll
                for (int mi = 0; mi < 4; mi++)
                    acc2[mi][ni] = MFMA16(af[mi], bv, acc2[mi][ni]);
            }
        }
        __syncthreads();
    }
#pragma unroll
    for (int ni = 0; ni < 4; ni++) {
        int n = wave * 64 + ni * 16 + l16;
        float bias = bfc2[n];
#pragma unroll
        for (int mi = 0; mi < 4; mi++) {
#pragma unroll
            for (int r = 0; r < 4; r++) {
                long long row = m0 + mi * 16 + quad * 4 + r;
                float xv = xio[row * 256 + n];
                xio[row * 256 + n] = xv + acc2[mi][ni][r] + bias;
            }
        }
    }
}

extern "C" void kernel_launch(void* const* d_in, const int* in_sizes, int n_in,
                              void* d_out, int out_size, void* d_ws, size_t ws_size,
                              hipStream_t stream) {
    const float* x      = (const float*)d_in[0];
    const float* ln1_g  = (const float*)d_in[1];
    const float* ln1_b  = (const float*)d_in[2];
    const float* ln2_g  = (const float*)d_in[3];
    const float* ln2_b  = (const float*)d_in[4];
    const float* rpe    = (const float*)d_in[5];
    const float* w_down = (const float*)d_in[6];
    const float* b_down = (const float*)d_in[7];
    const float* w_up   = (const float*)d_in[8];
    const float* b_up   = (const float*)d_in[9];
    const float* w_qkv  = (const float*)d_in[10];
    const float* b_qkv  = (const float*)d_in[11];
    const float* w_proj = (const float*)d_in[12];
    const float* b_proj = (const float*)d_in[13];
    const float* w_fc1  = (const float*)d_in[14];
    const float* b_fc1  = (const float*)d_in[15];
    const float* w_fc2  = (const float*)d_in[16];
    const float* b_fc2  = (const float*)d_in[17];
    float* out = (float*)d_out;

    char* wp = (char*)d_ws;
    auto alloc = [&](size_t bytes) { void* p = (void*)wp; wp += (bytes + 255) & ~(size_t)255; return p; };
    unsigned short* wdown_bf = (unsigned short*)alloc(4194304 * 2);
    unsigned short* wup_bf   = (unsigned short*)alloc(4194304 * 2);
    unsigned short* wqkv_bf  = (unsigned short*)alloc(196608 * 2);
    unsigned short* wproj_bf = (unsigned short*)alloc(65536 * 2);
    unsigned short* wfc1_bf  = (unsigned short*)alloc(262144 * 2);
    unsigned short* wfc2_bf  = (unsigned short*)alloc(262144 * 2);
    unsigned short* ydown    = (unsigned short*)alloc(524288 * 2);
    unsigned short* qb       = (unsigned short*)alloc(524288 * 2);
    unsigned short* kb       = (unsigned short*)alloc(524288 * 2);
    unsigned short* vT       = (unsigned short*)alloc(524288 * 2);
    unsigned short* obf      = (unsigned short*)alloc(524288 * 2);
    unsigned short* oproj    = (unsigned short*)alloc(524288 * 2);

    // Big temporaries live inside d_out (134.2 MB); all dead before k_up_fold
    // overwrites the whole buffer with x2.
    //   xln:  [0, 67.1 MB)        -- dead after k_gemm_down2
    //   S:    [0, 67.1 MB)        -- aliases xln (disjoint lifetime)
    //   P:    [67.1, 100.7 MB)
    //   part: [100.7, 134.2 MB)   -- 16 x 2 MB fp32 split-K partials, dead after k_red
    unsigned short* xln = (unsigned short*)d_out;
    float* S            = (float*)d_out;
    unsigned short* P   = (unsigned short*)((char*)d_out + 67108864);
    float* part         = (float*)((char*)d_out + 100663296);

    k_cvt<<<4096, 256, 0, stream>>>(w_down, wdown_bf, 4194304);
    k_cvt<<<4096, 256, 0, stream>>>(w_up, wup_bf, 4194304);
    k_cvt<<<192, 256, 0, stream>>>(w_qkv, wqkv_bf, 196608);
    k_cvt<<<64, 256, 0, stream>>>(w_proj, wproj_bf, 65536);
    k_cvt<<<256, 256, 0, stream>>>(w_fc1, wfc1_bf, 262144);
    k_cvt<<<256, 256, 0, stream>>>(w_fc2, wfc2_bf, 262144);

    k_ln_bf<<<32768, 256, 0, stream>>>(x, ln1_g, ln1_b, xln);
    k_gemm_down2<<<dim3(16, 2, 16), 256, 0, stream>>>(xln, wdown_bf, part);
    k_red<<<512, 256, 0, stream>>>(part, b_down, ydown);
    k_gemm_qkv<<<dim3(32, 12), 256, 0, stream>>>(ydown, wqkv_bf, b_qkv, qb, kb, vT);
    k_score<<<dim3(16, 16, 16), 256, 0, stream>>>(qb, kb, rpe, S);
    k_softmax<<<4096, 256, 0, stream>>>(S, P);
    k_pv<<<dim3(16, 16), 256, 0, stream>>>(P, vT, obf);
    k_gemm_proj<<<dim3(32, 4), 256, 0, stream>>>(obf, wproj_bf, b_proj, oproj);
    k_up_fold<<<dim3(32, 256), 256, 0, stream>>>(oproj, wup_bf, b_up, x, out);
    k_mlp<<<2048, 256, 0, stream>>>(out, ln2_g, ln2_b, wfc1_bf, b_fc1, wfc2_bf, b_fc2);
}